// Round 5
// baseline (52.848 us; speedup 1.0000x reference)
//
#include <hip/hip_runtime.h>

// Shapes fixed by setup_inputs(): B=4, L=1024, A=5, KNN=32, K=16.
// Output: [B, L, KNN, A*A*K] f32 = 52,428,800 elements (209.7 MB) — write-bound.
// R1: per-thread 64B stores -> 4x write-request amplification (69us).
// R2: lane-contiguous float4 stores -> 48us (65% of write floor).
// R4: fewer waves + nt stores -> 46us. Limiter is NOT wave overhead/cache
//     alloc: it's L1/TA gather serialization (~10 line-lookups per
//     (edge,pair), x4 redundant lanes = ~53us of TA occupancy).
// R5: two-phase: gathers once per (edge,pair) into LDS (25x less gather
//     traffic), then LDS-broadcast fan-out with coalesced nt stores.
constexpr int A_DIM  = 5;
constexpr int PAIRS  = 25;    // A*A
constexpr int KNN    = 32;
constexpr int L_DIM  = 1024;
constexpr int B_DIM  = 4;
constexpr int EPB    = 64;            // edges per block
constexpr int QPB    = EPB * PAIRS;   // 1600 (edge,pair) per block
constexpr int F4PB   = QPB * 4;       // 6400 f32x4 per block
// 1/sqrt(2*3.1415926)  (reference uses pi literal 3.1415926)
constexpr float INV_SQRT_2PI = 0.39894228f;

typedef float f32x4 __attribute__((ext_vector_type(4)));

// d_ws layout (floats): [0..15] = means, [16..31] = 1/(|std|+0.01),
// [32..47] = inv * INV_SQRT_2PI.
__global__ __launch_bounds__(64) void setup_consts(
    const float* __restrict__ means, const float* __restrict__ stds,
    float* __restrict__ ws)
{
    const int k = threadIdx.x;
    if (k < 16) {
        const float sd  = fabsf(stds[k]) + 0.01f;
        const float inv = __builtin_amdgcn_rcpf(sd);   // ~1 ulp; threshold 3.3e-2
        ws[k]      = means[k];
        ws[16 + k] = inv;
        ws[32 + k] = inv * INV_SQRT_2PI;
    }
}

__global__ __launch_bounds__(256) void gauss_rbf_kernel(
    const float*  __restrict__ X,           // [B,L,A,3]
    const int*    __restrict__ E_idx,       // [B,L,KNN]
    const float*  __restrict__ mask_atoms,  // [B,L,A]
    const float*  __restrict__ mask_attend, // [B,L,KNN]
    const float*  __restrict__ mul,         // [A*A]
    const float*  __restrict__ bias,        // [A*A]
    const f32x4*  __restrict__ cst,         // d_ws: 12 f32x4s
    f32x4*        __restrict__ out4)        // [B*L*KNN*100] f32x4s
{
    __shared__ float x_lds[QPB];     // masked affine distance per (edge,pair)
    __shared__ float att_lds[EPB];   // mask_attend per edge

    const int      tid = threadIdx.x;
    const unsigned blk = blockIdx.x;
    const unsigned e0  = blk * EPB;

    // channel-quartet constants: c = tid&3 is constant across all 25 iters
    const int   c   = tid & 3;
    const f32x4 mu4 = cst[c];
    const f32x4 iv4 = cst[4 + c];
    const f32x4 co4 = cst[8 + c];

    if (tid < EPB) att_lds[tid] = mask_attend[e0 + tid];

    // ---- Phase 1: one thread per (edge,pair); gathers happen ONCE ----
#pragma unroll
    for (int w = 0; w < 7; ++w) {
        const int s = tid + 256 * w;          // 1600 = 6.25*256 -> tail at w=6
        if (s < QPB) {
            const unsigned g    = (unsigned)s / PAIRS;
            const int      pair = s - (int)g * PAIRS;
            const int      i    = pair / A_DIM;        // neighbor atom
            const int      j    = pair - i * A_DIM;    // center atom

            const unsigned e  = e0 + g;
            const unsigned bl = e >> 5;                // b*L + l  (KNN=32)
            const unsigned b  = bl >> 10;              // L=1024
            const int      n  = E_idx[e];
            const unsigned bn = (b << 10) | (unsigned)n;

            const float* xn = X + ((size_t)bn * A_DIM + i) * 3;
            const float* xc = X + ((size_t)bl * A_DIM + j) * 3;
            const float dx = xn[0] - xc[0];
            const float dy = xn[1] - xc[1];
            const float dz = xn[2] - xc[2];
            const float D  = sqrtf(dx * dx + dy * dy + dz * dz);

            // both masks gathered at the NEIGHBOR residue (per reference)
            const float mi = mask_atoms[(size_t)bn * A_DIM + i];
            const float mj = mask_atoms[(size_t)bn * A_DIM + j];

            x_lds[s] = (mul[pair] * D + bias[pair]) * (mi * mj);
        }
    }
    __syncthreads();

    // ---- Phase 2: fan-out 4 channels/thread, LDS broadcasts, nt stores ----
    const int tq = tid >> 2;   // (edge,pair) slot served by this thread's quad
#pragma unroll 5
    for (int u = 0; u < 25; ++u) {
        const int      q   = tq + 64 * u;          // 0..1599
        const unsigned g   = (unsigned)q / PAIRS;  // edge within block
        const float    x   = x_lds[q];             // 4-lane broadcast
        const float    att = att_lds[g];

        const float z0 = (x - mu4.x) * iv4.x;
        const float z1 = (x - mu4.y) * iv4.y;
        const float z2 = (x - mu4.z) * iv4.z;
        const float z3 = (x - mu4.w) * iv4.w;
        f32x4 o;
        o.x = (co4.x * att) * __expf(-0.5f * z0 * z0);
        o.y = (co4.y * att) * __expf(-0.5f * z1 * z1);
        o.z = (co4.z * att) * __expf(-0.5f * z2 * z2);
        o.w = (co4.w * att) * __expf(-0.5f * z3 * z3);

        // wave writes one contiguous 1 KB per instr; nt = no cache allocate
        __builtin_nontemporal_store(o, &out4[(size_t)blk * F4PB + tid + 256 * u]);
    }
}

extern "C" void kernel_launch(void* const* d_in, const int* in_sizes, int n_in,
                              void* d_out, int out_size, void* d_ws, size_t ws_size,
                              hipStream_t stream) {
    const float* X           = (const float*)d_in[0];
    const int*   E_idx       = (const int*)  d_in[1];
    const float* mask_atoms  = (const float*)d_in[2];
    const float* mask_attend = (const float*)d_in[3];
    const float* means       = (const float*)d_in[4];
    const float* stds        = (const float*)d_in[5];
    const float* mul         = (const float*)d_in[6];
    const float* bias        = (const float*)d_in[7];
    float*       ws          = (float*)d_ws;
    f32x4*       out4        = (f32x4*)d_out;

    setup_consts<<<1, 64, 0, stream>>>(means, stds, ws);

    const int n_edges = B_DIM * L_DIM * KNN;   // 131,072
    const int grid    = n_edges / EPB;         // 2048 blocks (exact)

    gauss_rbf_kernel<<<grid, 256, 0, stream>>>(
        X, E_idx, mask_atoms, mask_attend, mul, bias,
        (const f32x4*)ws, out4);
}

// Round 6
// 50.920 us; speedup vs baseline: 1.0379x; 1.0379x over previous
//
#include <hip/hip_runtime.h>

// Shapes fixed by setup_inputs(): B=4, L=1024, A=5, KNN=32, K=16.
// Output: [B, L, KNN, A*A*K] f32 = 209.7 MB — write-bound (floor ~31us @6.9TB/s).
// R1: 64B/thread stores -> 4x write amplification (69us).
// R2: lane-contiguous f32x4 stores -> 48us. R4: +nt, fewer waves -> 46us.
// R5: LDS two-phase REGRESSED (52.8us) -> gather-instruction count is not the
//     limiter; barrier+LDS round-trip costs more than it saves.
// R6: split kernels. A: all gathers once per edge -> x[] in d_ws (13.1MB).
//     B: pure stream: 1-line coalesced x reads + nt stores. Discriminates
//     "load path steals from store path" vs "store ceiling is structural".
constexpr int A_DIM   = 5;
constexpr int PAIRS   = 25;    // A*A
constexpr int KNN     = 32;
constexpr int L_DIM   = 1024;
constexpr int B_DIM   = 4;
constexpr int N_EDGES = B_DIM * L_DIM * KNN;   // 131,072
// 1/sqrt(2*3.1415926)  (reference uses pi literal 3.1415926)
constexpr float INV_SQRT_2PI = 0.39894228f;

typedef float f32x4 __attribute__((ext_vector_type(4)));

// ws layout (floats): [0..15]=means, [16..31]=1/(|std|+0.01), [32..47]=inv*C,
// [48 ..48+3276800) = x[e*25+pair]   (13.1 MB + 192 B total)

// ---- Phase A: one thread per edge; every scattered gather happens ONCE ----
__global__ __launch_bounds__(256) void edge_x_kernel(
    const float* __restrict__ X,           // [B,L,A,3] (= [B*L][15])
    const int*   __restrict__ E_idx,       // [B,L,KNN]
    const float* __restrict__ mask_atoms,  // [B,L,A]
    const float* __restrict__ means,       // [16]
    const float* __restrict__ stds,        // [16]
    const float* __restrict__ mul,         // [25]
    const float* __restrict__ bias,        // [25]
    float*       __restrict__ ws)
{
    // fold channel-const setup into block 0 (no separate launch)
    if (blockIdx.x == 0 && threadIdx.x < 16) {
        const int   k   = threadIdx.x;
        const float sd  = fabsf(stds[k]) + 0.01f;
        const float inv = __builtin_amdgcn_rcpf(sd);   // ~1 ulp; thr 3.3e-2
        ws[k]      = means[k];
        ws[16 + k] = inv;
        ws[32 + k] = inv * INV_SQRT_2PI;
    }

    const unsigned e  = blockIdx.x * 256u + threadIdx.x;   // coalesced
    const unsigned bl = e >> 5;                 // b*L + l  (KNN=32); 2 per wave
    const unsigned b  = bl >> 10;               // L=1024
    const int      n  = E_idx[e];               // 1 coalesced line
    const unsigned bn = (b << 10) | (unsigned)n;

    const float* Xn = X + (size_t)bn * 15;      // neighbor residue atoms
    const float* Xc = X + (size_t)bl * 15;      // center residue (wave-uniform-ish)
    float xn[15], xc[15], m[5];
#pragma unroll
    for (int t = 0; t < 15; ++t) { xn[t] = Xn[t]; xc[t] = Xc[t]; }
#pragma unroll
    for (int t = 0; t < 5; ++t) m[t] = mask_atoms[(size_t)bn * 5 + t];

    float* xo = ws + 48 + (size_t)e * PAIRS;
#pragma unroll
    for (int i = 0; i < 5; ++i) {          // neighbor atom
#pragma unroll
        for (int j = 0; j < 5; ++j) {      // center atom
            const float dx = xn[3*i]   - xc[3*j];
            const float dy = xn[3*i+1] - xc[3*j+1];
            const float dz = xn[3*i+2] - xc[3*j+2];
            const float D  = sqrtf(dx*dx + dy*dy + dz*dz);
            const int   p  = i * 5 + j;
            // mask_pair = mask_na[i]*mask_na[j], both at NEIGHBOR residue
            xo[p] = (mul[p] * D + bias[p]) * (m[i] * m[j]);
        }
    }
}

// ---- Phase B: pure stream. x: 1 aligned line/wave-load; nt f32x4 stores ----
__global__ __launch_bounds__(256) void rbf_write_kernel(
    const float* __restrict__ ws,
    const float* __restrict__ mask_attend,  // [B,L,KNN]
    f32x4*       __restrict__ out4)         // 13,107,200 f32x4s
{
    const int tid = threadIdx.x;
    const int c   = tid & 3;                // channel quartet, loop-invariant
    const f32x4* cst = (const f32x4*)ws;
    const f32x4 mu4 = cst[c];
    const f32x4 iv4 = cst[4 + c];
    const f32x4 co4 = cst[8 + c];
    const float* xw = ws + 48;

    const unsigned fbase = blockIdx.x * 1024u + (unsigned)tid;

#pragma unroll
    for (int u = 0; u < 4; ++u) {
        const unsigned fidx = fbase + 256u * u;  // f32x4 index
        const unsigned q    = fidx >> 2;         // (edge,pair): 16 consec dwords/wave
        const unsigned e    = q / PAIRS;         // magic-mul; 1-2 lines/wave
        const float    x    = xw[q];             // ONE aligned 64B line per wave
        const float    att  = mask_attend[e];

        const float z0 = (x - mu4.x) * iv4.x;
        const float z1 = (x - mu4.y) * iv4.y;
        const float z2 = (x - mu4.z) * iv4.z;
        const float z3 = (x - mu4.w) * iv4.w;
        f32x4 o;
        o.x = (co4.x * att) * __expf(-0.5f * z0 * z0);
        o.y = (co4.y * att) * __expf(-0.5f * z1 * z1);
        o.z = (co4.z * att) * __expf(-0.5f * z2 * z2);
        o.w = (co4.w * att) * __expf(-0.5f * z3 * z3);

        // lane-contiguous 1 KB per wave-store, no cache allocate
        __builtin_nontemporal_store(o, &out4[fidx]);
    }
}

extern "C" void kernel_launch(void* const* d_in, const int* in_sizes, int n_in,
                              void* d_out, int out_size, void* d_ws, size_t ws_size,
                              hipStream_t stream) {
    const float* X           = (const float*)d_in[0];
    const int*   E_idx       = (const int*)  d_in[1];
    const float* mask_atoms  = (const float*)d_in[2];
    const float* mask_attend = (const float*)d_in[3];
    const float* means       = (const float*)d_in[4];
    const float* stds        = (const float*)d_in[5];
    const float* mul         = (const float*)d_in[6];
    const float* bias        = (const float*)d_in[7];
    float*       ws          = (float*)d_ws;
    f32x4*       out4        = (f32x4*)d_out;

    edge_x_kernel<<<N_EDGES / 256, 256, 0, stream>>>(
        X, E_idx, mask_atoms, means, stds, mul, bias, ws);

    const int total_f4 = N_EDGES * PAIRS * 4;   // 13,107,200
    rbf_write_kernel<<<total_f4 / 1024, 256, 0, stream>>>(
        ws, mask_attend, out4);
}

// Round 7
// 47.609 us; speedup vs baseline: 1.1100x; 1.0695x over previous
//
#include <hip/hip_runtime.h>

// Shapes fixed by setup_inputs(): B=4, L=1024, A=5, KNN=32, K=16.
// Output: [B, L, KNN, A*A*K] f32 = 209.7 MB — write-bound (fill floor ~31us).
// R1: 64B/thread stores -> 4x write amplification (69us).
// R2: lane-contiguous f32x4 stores -> 48us. R4: +nt, 4 f4/thread -> 46us.
// R5: LDS two-phase regressed (52.8) -> gather count not the limiter.
// R6: split kernels regressed (50.9); pure coalesced-load+store stream ALSO
//     ~4.6 TB/s -> load path exonerated. fillBuffer hits 6.9 TB/s at 3-4
//     waves/CU => long-lived waves streaming contiguous stores.
// R7: fillBuffer-shaped writer: 32 f32x4/thread, wave-linear order -> each
//     wave streams 32KB contiguous in 32 back-to-back 1KB stores; 1600
//     long-lived blocks instead of 12800 short ones. Gather side = R4.
constexpr int A_DIM   = 5;
constexpr int PAIRS   = 25;    // A*A
constexpr int KNN     = 32;
constexpr int L_DIM   = 1024;
constexpr int B_DIM   = 4;
constexpr int N_EDGES = B_DIM * L_DIM * KNN;        // 131,072
constexpr int TOTAL_F4 = N_EDGES * PAIRS * 4;       // 13,107,200 f32x4
constexpr int F4_PER_THREAD = 32;                   // 512 B per thread
constexpr int F4_PER_BLOCK  = 256 * F4_PER_THREAD;  // 8192 (128 KB contiguous)
// 1/sqrt(2*3.1415926)  (reference uses pi literal 3.1415926)
constexpr float INV_SQRT_2PI = 0.39894228f;

typedef float f32x4 __attribute__((ext_vector_type(4)));

__global__ __launch_bounds__(256) void gauss_rbf_kernel(
    const float* __restrict__ X,           // [B,L,A,3]
    const int*   __restrict__ E_idx,       // [B,L,KNN]
    const float* __restrict__ mask_atoms,  // [B,L,A]
    const float* __restrict__ mask_attend, // [B,L,KNN]
    const float* __restrict__ means,       // [16]
    const float* __restrict__ stds,        // [16]
    const float* __restrict__ mul,         // [25]
    const float* __restrict__ bias,        // [25]
    f32x4*       __restrict__ out4)        // 13,107,200 f32x4s
{
    const int tid  = threadIdx.x;
    const int lane = tid & 63;
    const int wave = tid >> 6;
    const int c    = lane & 3;             // channel quartet, loop-invariant

    // per-thread channel constants (4 broadcast-ish lines; once per 32 iters)
    f32x4 mu4, iv4, co4;
#pragma unroll
    for (int t = 0; t < 4; ++t) {
        const int   k   = c * 4 + t;
        const float sd  = fabsf(stds[k]) + 0.01f;
        const float inv = __builtin_amdgcn_rcpf(sd);   // ~1 ulp; thr 3.3e-2
        mu4[t] = means[k];
        iv4[t] = inv;
        co4[t] = inv * INV_SQRT_2PI;
    }

    // wave-linear: wave streams [wbase, wbase+2048) f32x4 = 32 KB contiguous
    const unsigned wbase = blockIdx.x * (unsigned)F4_PER_BLOCK
                         + (unsigned)wave * 2048u + (unsigned)lane;

#pragma unroll 4
    for (int it = 0; it < F4_PER_THREAD; ++it) {
        const unsigned fidx = wbase + (unsigned)it * 64u;  // f32x4 index
        const unsigned q    = fidx >> 2;          // (edge,pair); 16 consec/wave
        const unsigned e    = q / PAIRS;          // magic-mul
        const int      pair = (int)(q - e * PAIRS);
        const int      i    = pair / A_DIM;       // neighbor atom
        const int      j    = pair - i * A_DIM;   // center atom

        const unsigned bl = e >> 5;               // b*L + l  (KNN=32)
        const unsigned b  = bl >> 10;             // L=1024
        const int      n  = E_idx[e];
        const unsigned bn = (b << 10) | (unsigned)n;

        // L1/L2-resident gathers; a wave-iter touches 1-2 edges
        const float* xn = X + ((size_t)bn * A_DIM + i) * 3;
        const float* xc = X + ((size_t)bl * A_DIM + j) * 3;
        const float dx = xn[0] - xc[0];
        const float dy = xn[1] - xc[1];
        const float dz = xn[2] - xc[2];
        const float D  = sqrtf(dx * dx + dy * dy + dz * dz);

        // both masks gathered at the NEIGHBOR residue (per reference)
        const float mi = mask_atoms[(size_t)bn * A_DIM + i];
        const float mj = mask_atoms[(size_t)bn * A_DIM + j];

        const float x   = (mul[pair] * D + bias[pair]) * (mi * mj);
        const float att = mask_attend[e];

        const float z0 = (x - mu4.x) * iv4.x;
        const float z1 = (x - mu4.y) * iv4.y;
        const float z2 = (x - mu4.z) * iv4.z;
        const float z3 = (x - mu4.w) * iv4.w;
        f32x4 o;
        o.x = (co4.x * att) * __expf(-0.5f * z0 * z0);
        o.y = (co4.y * att) * __expf(-0.5f * z1 * z1);
        o.z = (co4.z * att) * __expf(-0.5f * z2 * z2);
        o.w = (co4.w * att) * __expf(-0.5f * z3 * z3);

        // contiguous 1 KB wave-store; 32 back-to-back per wave = 32 KB stream
        __builtin_nontemporal_store(o, &out4[fidx]);
    }
}

extern "C" void kernel_launch(void* const* d_in, const int* in_sizes, int n_in,
                              void* d_out, int out_size, void* d_ws, size_t ws_size,
                              hipStream_t stream) {
    const float* X           = (const float*)d_in[0];
    const int*   E_idx       = (const int*)  d_in[1];
    const float* mask_atoms  = (const float*)d_in[2];
    const float* mask_attend = (const float*)d_in[3];
    const float* means       = (const float*)d_in[4];
    const float* stds        = (const float*)d_in[5];
    const float* mul         = (const float*)d_in[6];
    const float* bias        = (const float*)d_in[7];
    f32x4*       out4        = (f32x4*)d_out;

    const int grid = TOTAL_F4 / F4_PER_BLOCK;   // 1600 blocks (exact)

    gauss_rbf_kernel<<<grid, 256, 0, stream>>>(
        X, E_idx, mask_atoms, mask_attend, means, stds, mul, bias, out4);
}